// Round 11
// baseline (110.199 us; speedup 1.0000x reference)
//
#include <hip/hip_runtime.h>
#include <hip/hip_fp16.h>

#define B 32
#define O 64
#define M 128
#define H 4
#define E 64
#define SC 2.88539008177792681f     // 2*log2(e): tanh(x) = 1 - 2/(1+exp2(SC*x))
#define LOG2E 1.44269504088896341f

#if __has_builtin(__builtin_amdgcn_exp2f)
#define EXP2F(x) __builtin_amdgcn_exp2f(x)
#else
#define EXP2F(x) __exp2f(x)
#endif

__device__ __forceinline__ unsigned pk2h(float a, float b) {
    return (unsigned)__half_as_ushort(__float2half_rn(a)) |
           ((unsigned)__half_as_ushort(__float2half_rn(b)) << 16);
}

// ============ prep: blocks 0..31: ctx -> Ec = half(exp2(SC*c)) transposed [e][m],
//   mem -> fp16 transposed [e][m].
//   blocks 32..543: qw_tab[pair][h*64+e] = (w_e, Eq_bo0, Eq_bo1, 0), 4 rows/block ====
__global__ __launch_bounds__(256) void prep_kernel(
    const float* __restrict__ query, const float* __restrict__ context,
    const float* __restrict__ memory, const float* __restrict__ W_ch,
    const float* __restrict__ b_ch, const float* __restrict__ w_logit,
    __half* __restrict__ ctx_Eh, __half* __restrict__ mem_T, float4* __restrict__ qw_tab)
{
    __shared__ float s[128 * 68];          // tile staged stride-68
    const int t = threadIdx.x, blk = blockIdx.x;

    if (blk < 32) {
        const int b = blk;
        const int e = t >> 2, mb = (t & 3) * 32;
        // ---- pass 1: ctx -> exp-space fp16 transposed ----
        const float* ctx = context + b * (M * E);
        #pragma unroll
        for (int i = 0; i < 8; ++i) {
            int idx = i * 1024 + t * 4;
            float4 v = *(const float4*)(ctx + idx);
            *(float4*)(&s[(idx >> 6) * 68 + (idx & 63)]) = v;
        }
        __syncthreads();
        {
            uint4* dst = (uint4*)(ctx_Eh + (size_t)b * (E * M) + e * M + mb);
            #pragma unroll
            for (int qd = 0; qd < 4; ++qd) {
                unsigned u[4];
                #pragma unroll
                for (int k = 0; k < 4; ++k) {
                    int m0 = mb + qd * 8 + 2 * k;
                    float ea = fminf(EXP2F(SC * s[m0 * 68 + e]), 60000.f);
                    float eb = fminf(EXP2F(SC * s[(m0 + 1) * 68 + e]), 60000.f);
                    u[k] = pk2h(ea, eb);
                }
                dst[qd] = make_uint4(u[0], u[1], u[2], u[3]);
            }
        }
        __syncthreads();
        // ---- pass 2: mem -> fp16 transposed ----
        const float* mem = memory + b * (M * E);
        #pragma unroll
        for (int i = 0; i < 8; ++i) {
            int idx = i * 1024 + t * 4;
            float4 v = *(const float4*)(mem + idx);
            *(float4*)(&s[(idx >> 6) * 68 + (idx & 63)]) = v;
        }
        __syncthreads();
        {
            uint4* dst = (uint4*)(mem_T + (size_t)b * (E * M) + e * M + mb);
            #pragma unroll
            for (int qd = 0; qd < 4; ++qd) {
                unsigned u[4];
                #pragma unroll
                for (int k = 0; k < 4; ++k) {
                    int m0 = mb + qd * 8 + 2 * k;
                    u[k] = pk2h(s[m0 * 68 + e], s[(m0 + 1) * 68 + e]);
                }
                dst[qd] = make_uint4(u[0], u[1], u[2], u[3]);
            }
        }
    } else {
        const int r0 = (blk - 32) * 4;      // 4 query rows (bo); pairs r0/2, r0/2+1
        s[t] = query[(r0 + (t & 3)) * 64 + (t >> 2)];
        __syncthreads();
        float bc = b_ch[t];
        float a0 = bc, a1 = bc, a2 = bc, a3 = bc;
        #pragma unroll 8
        for (int k = 0; k < 64; ++k) {
            float4 qv = *(const float4*)(&s[k * 4]);   // uniform ds_read_b128
            float wv = W_ch[k * 256 + t];
            a0 = fmaf(qv.x, wv, a0);
            a1 = fmaf(qv.y, wv, a1);
            a2 = fmaf(qv.z, wv, a2);
            a3 = fmaf(qv.w, wv, a3);
        }
        const float wl = w_logit[t & 63];
        const int p0 = r0 >> 1;
        qw_tab[(size_t)p0 * 256 + t]       = make_float4(wl, EXP2F(SC * a0), EXP2F(SC * a1), 0.f);
        qw_tab[(size_t)(p0 + 1) * 256 + t] = make_float4(wl, EXP2F(SC * a2), EXP2F(SC * a3), 0.f);
    }
}

// ============ main: LDS-pipe evacuated. ctx from global (L2-hot, VMEM pipe),
//   q/w from qw_tab via wave-uniform s_load (scalar pipe). LDS only for
//   probs + cross-wave partials (12 KB). 2 o's per block. ====
__global__ __launch_bounds__(256) void attn_main(
    const __half* __restrict__ ctx_Eh, const __half* __restrict__ mem_T,
    const float4* __restrict__ qw_tab, const float* __restrict__ w_logit,
    const float* __restrict__ b_logit, const float* __restrict__ temp,
    __half* __restrict__ heads_h)
{
    __shared__ float s_prob0[M * H];     // 2 KB
    __shared__ float s_prob1[M * H];     // 2 KB
    __shared__ float s_part0[H * 4 * E]; // 4 KB  [h][wave][e]
    __shared__ float s_part1[H * 4 * E]; // 4 KB   -> 12 KB total

    const int t = threadIdx.x, lane = t & 63, w = t >> 6;
    const int bo0 = blockIdx.x * 2, bo1 = bo0 + 1, b = bo0 >> 6;

    const float wl = w_logit[lane];
    float sumw = wl;
    #pragma unroll
    for (int sft = 1; sft < 64; sft <<= 1) sumw += __shfl_xor(sumw, sft);
    const float bl   = b_logit[0];
    const float lsc  = LOG2E / temp[0];
    const float base = (sumw + bl) * lsc;   // logit = base + lsc2*acc
    const float lsc2 = -2.0f * lsc;

    // tanh+logit: wave w = head, lane covers m = 2*lane, 2*lane+1.
    // ctx: coalesced global dword (L2-hot). q/w: wave-uniform float4 -> s_load.
    float a00 = 0.f, a01 = 0.f, a10 = 0.f, a11 = 0.f;
    {
        const __half2* cg = (const __half2*)(ctx_Eh + (size_t)b * (E * M));
        const float4*  qw = qw_tab + (size_t)blockIdx.x * 256 + w * 64;
        #pragma unroll 8
        for (int e = 0; e < 64; ++e) {
            float2 cf = __half22float2(cg[e * 64 + lane]);
            float4 q  = qw[e];                      // uniform -> scalar pipe
            float t00 = fmaf(cf.x, q.y, 1.0f);
            float t01 = fmaf(cf.y, q.y, 1.0f);
            float t10 = fmaf(cf.x, q.z, 1.0f);
            float t11 = fmaf(cf.y, q.z, 1.0f);
            float r0 = __builtin_amdgcn_rcpf(t00 * t01);
            float r1 = __builtin_amdgcn_rcpf(t10 * t11);
            float w0 = q.x * r0;
            float w1 = q.x * r1;
            a00 = fmaf(w0, t01, a00);  a01 = fmaf(w0, t00, a01);
            a10 = fmaf(w1, t11, a10);  a11 = fmaf(w1, t10, a11);
        }
    }

    // prefetch mem_T fragment (32 halves: m = 32w..32w+31 at e = lane)
    uint4 mr[4];
    {
        const uint4* mp = (const uint4*)(mem_T + (size_t)b * (E * M) + lane * M + 32 * w);
        mr[0] = mp[0]; mr[1] = mp[1]; mr[2] = mp[2]; mr[3] = mp[3];
    }

    // softmax for both o's (wave butterflies, interleaved)
    float l00 = fmaf(lsc2, a00, base), l01 = fmaf(lsc2, a01, base);
    float l10 = fmaf(lsc2, a10, base), l11 = fmaf(lsc2, a11, base);
    float mx0 = fmaxf(l00, l01), mx1 = fmaxf(l10, l11);
    #pragma unroll
    for (int sft = 1; sft < 64; sft <<= 1) {
        mx0 = fmaxf(mx0, __shfl_xor(mx0, sft));
        mx1 = fmaxf(mx1, __shfl_xor(mx1, sft));
    }
    float e00 = EXP2F(l00 - mx0), e01 = EXP2F(l01 - mx0);
    float e10 = EXP2F(l10 - mx1), e11 = EXP2F(l11 - mx1);
    float s0 = e00 + e01, s1 = e10 + e11;
    #pragma unroll
    for (int sft = 1; sft < 64; sft <<= 1) {
        s0 += __shfl_xor(s0, sft);
        s1 += __shfl_xor(s1, sft);
    }
    float rs0 = __builtin_amdgcn_rcpf(s0), rs1 = __builtin_amdgcn_rcpf(s1);
    s_prob0[(2 * lane) * H + w]     = e00 * rs0;
    s_prob0[(2 * lane + 1) * H + w] = e01 * rs0;
    s_prob1[(2 * lane) * H + w]     = e10 * rs1;
    s_prob1[(2 * lane + 1) * H + w] = e11 * rs1;
    __syncthreads();

    // heads: wave w covers m in [32w,32w+32), all 4 heads, both o's, lane = e
    float h00 = 0.f, h01 = 0.f, h02 = 0.f, h03 = 0.f;
    float h10 = 0.f, h11 = 0.f, h12 = 0.f, h13 = 0.f;
    {
        union { uint4 u4[4]; __half2 h2[16]; } mu;
        mu.u4[0] = mr[0]; mu.u4[1] = mr[1]; mu.u4[2] = mr[2]; mu.u4[3] = mr[3];
        const int mbase = 32 * w;
        #pragma unroll 8
        for (int j = 0; j < 16; ++j) {
            float2 mv = __half22float2(mu.h2[j]);
            int m = mbase + 2 * j;
            float4 pa = *(const float4*)(&s_prob0[m * 4]);
            float4 pb = *(const float4*)(&s_prob0[(m + 1) * 4]);
            h00 = fmaf(pa.x, mv.x, h00); h01 = fmaf(pa.y, mv.x, h01);
            h02 = fmaf(pa.z, mv.x, h02); h03 = fmaf(pa.w, mv.x, h03);
            h00 = fmaf(pb.x, mv.y, h00); h01 = fmaf(pb.y, mv.y, h01);
            h02 = fmaf(pb.z, mv.y, h02); h03 = fmaf(pb.w, mv.y, h03);
            float4 pc = *(const float4*)(&s_prob1[m * 4]);
            float4 pd = *(const float4*)(&s_prob1[(m + 1) * 4]);
            h10 = fmaf(pc.x, mv.x, h10); h11 = fmaf(pc.y, mv.x, h11);
            h12 = fmaf(pc.z, mv.x, h12); h13 = fmaf(pc.w, mv.x, h13);
            h10 = fmaf(pd.x, mv.y, h10); h11 = fmaf(pd.y, mv.y, h11);
            h12 = fmaf(pd.z, mv.y, h12); h13 = fmaf(pd.w, mv.y, h13);
        }
    }
    s_part0[0 * 256 + w * 64 + lane] = h00;
    s_part0[1 * 256 + w * 64 + lane] = h01;
    s_part0[2 * 256 + w * 64 + lane] = h02;
    s_part0[3 * 256 + w * 64 + lane] = h03;
    s_part1[0 * 256 + w * 64 + lane] = h10;
    s_part1[1 * 256 + w * 64 + lane] = h11;
    s_part1[2 * 256 + w * 64 + lane] = h12;
    s_part1[3 * 256 + w * 64 + lane] = h13;
    __syncthreads();
    // final: thread t -> (h = w, e = lane); leaky relu; fp16 stores
    float hv0 = s_part0[w * 256 + lane] + s_part0[w * 256 + 64 + lane]
              + s_part0[w * 256 + 128 + lane] + s_part0[w * 256 + 192 + lane];
    float hv1 = s_part1[w * 256 + lane] + s_part1[w * 256 + 64 + lane]
              + s_part1[w * 256 + 128 + lane] + s_part1[w * 256 + 192 + lane];
    hv0 = (hv0 > 0.f) ? hv0 : 0.01f * hv0;
    hv1 = (hv1 > 0.f) ? hv1 : 0.01f * hv1;
    heads_h[(size_t)bo0 * 256 + t] = __float2half_rn(hv0);
    heads_h[(size_t)bo1 * 256 + t] = __float2half_rn(hv1);
}

// ============ post: out = heads @ W_rh + b_rh ; 4 rows/block, 512 blocks ====
__global__ __launch_bounds__(256) void post_kernel(
    const __half* __restrict__ heads_h, const float* __restrict__ W_rh,
    const float* __restrict__ b_rh, float* __restrict__ out)
{
    __shared__ __half s_h[4 * 256];     // 2KB
    const int t = threadIdx.x, lane = t & 63, r = t >> 6;   // wave = row
    const int r0 = blockIdx.x * 4;
    ((uint4*)s_h)[t & 127] = ((const uint4*)(heads_h + (size_t)r0 * 256))[t & 127];
    __syncthreads();
    const __half2* hr = (const __half2*)(s_h + r * 256);
    const float* Wp = W_rh + lane;
    float acc = 0.f;
    #pragma unroll 8
    for (int jp = 0; jp < 128; ++jp) {
        float2 hh = __half22float2(hr[jp]);    // uniform per wave
        acc = fmaf(hh.x, Wp[(2 * jp) * 64], acc);
        acc = fmaf(hh.y, Wp[(2 * jp + 1) * 64], acc);
    }
    out[(size_t)(r0 + r) * 64 + lane] = acc + b_rh[lane];
}

extern "C" void kernel_launch(void* const* d_in, const int* in_sizes, int n_in,
                              void* d_out, int out_size, void* d_ws, size_t ws_size,
                              hipStream_t stream) {
    const float* query   = (const float*)d_in[0];
    const float* context = (const float*)d_in[1];
    const float* memory  = (const float*)d_in[2];
    const float* W_ch    = (const float*)d_in[3];
    const float* b_ch    = (const float*)d_in[4];
    const float* w_logit = (const float*)d_in[5];
    const float* b_logit = (const float*)d_in[6];
    const float* W_rh    = (const float*)d_in[7];
    const float* b_rh    = (const float*)d_in[8];
    const float* temp    = (const float*)d_in[9];
    float* out = (float*)d_out;

    // workspace carve: ctx_Eh 512K | mem_T 512K | qw_tab 4M | heads_h 1M
    __half* ctx_Eh  = (__half*)d_ws;
    __half* mem_T   = ctx_Eh + (size_t)B * E * M;
    float4* qw_tab  = (float4*)(mem_T + (size_t)B * E * M);
    __half* heads_h = (__half*)(qw_tab + (size_t)1024 * 256);

    prep_kernel<<<544, 256, 0, stream>>>(query, context, memory, W_ch, b_ch,
                                         w_logit, ctx_Eh, mem_T, qw_tab);
    attn_main<<<B * O / 2, 256, 0, stream>>>(ctx_Eh, mem_T, qw_tab, w_logit,
                                             b_logit, temp, heads_h);
    post_kernel<<<512, 256, 0, stream>>>(heads_h, W_rh, b_rh, out);
}

// Round 12
// 99.164 us; speedup vs baseline: 1.1113x; 1.1113x over previous
//
#include <hip/hip_runtime.h>
#include <hip/hip_fp16.h>

#define B 32
#define O 64
#define M 128
#define H 4
#define E 64
#define SC 2.88539008177792681f     // 2*log2(e): tanh(x) = 1 - 2/(1+exp2(SC*x))
#define LOG2E 1.44269504088896341f

#if __has_builtin(__builtin_amdgcn_exp2f)
#define EXP2F(x) __builtin_amdgcn_exp2f(x)
#else
#define EXP2F(x) __exp2f(x)
#endif

__device__ __forceinline__ float rl(float v, int lane) {
    return __uint_as_float(__builtin_amdgcn_readlane(__float_as_uint(v), lane));
}
__device__ __forceinline__ unsigned pk2h(float a, float b) {
    return (unsigned)__half_as_ushort(__float2half_rn(a)) |
           ((unsigned)__half_as_ushort(__float2half_rn(b)) << 16);
}

// ============ prep (576 blocks): 0..31 ctx -> half(exp2(SC*c)) transposed [e][m];
//   32..63 mem -> fp16 transposed [e][m]; 64..575 q_E = exp2(SC*(qW+b)) f32 ====
__global__ __launch_bounds__(256) void prep_kernel(
    const float* __restrict__ query, const float* __restrict__ context,
    const float* __restrict__ memory, const float* __restrict__ W_ch,
    const float* __restrict__ b_ch,
    __half* __restrict__ ctx_Eh, __half* __restrict__ mem_T, float* __restrict__ q_E)
{
    __shared__ float s[128 * 68];          // tile staged stride-68
    const int t = threadIdx.x, blk = blockIdx.x;

    if (blk < 64) {
        const int b = blk & 31;
        const bool is_ctx = blk < 32;
        const int e = t >> 2, mb = (t & 3) * 32;
        const float* src = (is_ctx ? context : memory) + b * (M * E);
        #pragma unroll
        for (int i = 0; i < 8; ++i) {
            int idx = i * 1024 + t * 4;
            float4 v = *(const float4*)(src + idx);
            *(float4*)(&s[(idx >> 6) * 68 + (idx & 63)]) = v;
        }
        __syncthreads();
        if (is_ctx) {
            uint4* dst = (uint4*)(ctx_Eh + (size_t)b * (E * M) + e * M + mb);
            #pragma unroll
            for (int qd = 0; qd < 4; ++qd) {
                unsigned u[4];
                #pragma unroll
                for (int k = 0; k < 4; ++k) {
                    int m0 = mb + qd * 8 + 2 * k;
                    float ea = fminf(EXP2F(SC * s[m0 * 68 + e]), 60000.f);
                    float eb = fminf(EXP2F(SC * s[(m0 + 1) * 68 + e]), 60000.f);
                    u[k] = pk2h(ea, eb);
                }
                dst[qd] = make_uint4(u[0], u[1], u[2], u[3]);
            }
        } else {
            uint4* dst = (uint4*)(mem_T + (size_t)b * (E * M) + e * M + mb);
            #pragma unroll
            for (int qd = 0; qd < 4; ++qd) {
                unsigned u[4];
                #pragma unroll
                for (int k = 0; k < 4; ++k) {
                    int m0 = mb + qd * 8 + 2 * k;
                    u[k] = pk2h(s[m0 * 68 + e], s[(m0 + 1) * 68 + e]);
                }
                dst[qd] = make_uint4(u[0], u[1], u[2], u[3]);
            }
        }
    } else {
        const int r0 = (blk - 64) * 4;      // 4 query rows (bo indices)
        s[t] = query[(r0 + (t & 3)) * 64 + (t >> 2)];
        __syncthreads();
        float bc = b_ch[t];
        float a0 = bc, a1 = bc, a2 = bc, a3 = bc;
        #pragma unroll 8
        for (int k = 0; k < 64; ++k) {
            float4 qv = *(const float4*)(&s[k * 4]);   // uniform ds_read_b128
            float wv = W_ch[k * 256 + t];
            a0 = fmaf(qv.x, wv, a0);
            a1 = fmaf(qv.y, wv, a1);
            a2 = fmaf(qv.z, wv, a2);
            a3 = fmaf(qv.w, wv, a3);
        }
        float* qa = q_E + (size_t)r0 * 256 + t;
        qa[0]   = EXP2F(SC * a0);
        qa[256] = EXP2F(SC * a1);
        qa[512] = EXP2F(SC * a2);
        qa[768] = EXP2F(SC * a3);
    }
}

// ============ main: R10 structure + fused output projection (post kernel gone) ====
__global__ __launch_bounds__(256) void attn_main(
    const __half* __restrict__ ctx_Eh, const __half* __restrict__ mem_T,
    const float* __restrict__ q_E, const float* __restrict__ w_logit,
    const float* __restrict__ b_logit, const float* __restrict__ temp,
    const float* __restrict__ W_rh, const float* __restrict__ b_rh,
    float* __restrict__ out)
{
    __shared__ __half s_E[E * M];        // [e][m] Ec fp16, 16 KB
    __shared__ float4 s_qwu[H * E];      // (w, Eq0, Eq1, -) per head,e: 4 KB
    __shared__ float  s_prob0[M * H];    // 2 KB
    __shared__ float  s_prob1[M * H];    // 2 KB
    __shared__ float  s_part0[H * 4 * E];// 4 KB  [h][wave][e]
    __shared__ float  s_part1[H * 4 * E];// 4 KB
    __shared__ float  s_po0[4 * E];      // 1 KB  [wave][e'] out partials o0
    __shared__ float  s_po1[4 * E];      // 1 KB

    const int t = threadIdx.x, lane = t & 63, w = t >> 6;
    const int bo0 = blockIdx.x * 2, bo1 = bo0 + 1, b = bo0 >> 6;

    // stage ctx_Eh[b] (16 KB, dwordx4) + qw tuples
    {
        const uint4* g = (const uint4*)(ctx_Eh + (size_t)b * (E * M));
        uint4* l = (uint4*)s_E;
        #pragma unroll
        for (int p = 0; p < 4; ++p)
            l[p * 256 + t] = g[p * 256 + t];
    }
    const float wl = w_logit[lane];
    s_qwu[t] = make_float4(wl, q_E[bo0 * 256 + t], q_E[bo1 * 256 + t], 0.f);
    float sumw = wl;
    #pragma unroll
    for (int sft = 1; sft < 64; sft <<= 1) sumw += __shfl_xor(sumw, sft);
    const float bl   = b_logit[0];
    const float lsc  = LOG2E / temp[0];
    const float base = (sumw + bl) * lsc;   // logit = base + lsc2*acc
    const float lsc2 = -2.0f * lsc;
    __syncthreads();

    // tanh+logit: wave w = head, lane covers m = 2*lane, 2*lane+1, both o's.
    float a00 = 0.f, a01 = 0.f, a10 = 0.f, a11 = 0.f;
    const __half2* Ep = (const __half2*)s_E;
    const float4*  qp = &s_qwu[w * 64];
    #pragma unroll 4
    for (int e = 0; e < 64; ++e) {
        float2 cf = __half22float2(Ep[e * 64 + lane]);  // varying b32, 2-way free
        float4 qw = qp[e];                              // uniform b128 broadcast
        float t00 = fmaf(cf.x, qw.y, 1.0f);
        float t01 = fmaf(cf.y, qw.y, 1.0f);
        float t10 = fmaf(cf.x, qw.z, 1.0f);
        float t11 = fmaf(cf.y, qw.z, 1.0f);
        float r0 = __builtin_amdgcn_rcpf(t00 * t01);
        float r1 = __builtin_amdgcn_rcpf(t10 * t11);
        float w0 = qw.x * r0;
        float w1 = qw.x * r1;
        a00 = fmaf(w0, t01, a00);  a01 = fmaf(w0, t00, a01);
        a10 = fmaf(w1, t11, a10);  a11 = fmaf(w1, t10, a11);
    }

    // prefetch mem_T fragment (32 halves: m = 32w..32w+31 at e = lane)
    uint4 mr[4];
    {
        const uint4* mp = (const uint4*)(mem_T + (size_t)b * (E * M) + lane * M + 32 * w);
        mr[0] = mp[0]; mr[1] = mp[1]; mr[2] = mp[2]; mr[3] = mp[3];
    }

    // softmax for both o's (wave butterflies, interleaved)
    float l00 = fmaf(lsc2, a00, base), l01 = fmaf(lsc2, a01, base);
    float l10 = fmaf(lsc2, a10, base), l11 = fmaf(lsc2, a11, base);
    float mx0 = fmaxf(l00, l01), mx1 = fmaxf(l10, l11);
    #pragma unroll
    for (int sft = 1; sft < 64; sft <<= 1) {
        mx0 = fmaxf(mx0, __shfl_xor(mx0, sft));
        mx1 = fmaxf(mx1, __shfl_xor(mx1, sft));
    }
    float e00 = EXP2F(l00 - mx0), e01 = EXP2F(l01 - mx0);
    float e10 = EXP2F(l10 - mx1), e11 = EXP2F(l11 - mx1);
    float s0 = e00 + e01, s1 = e10 + e11;
    #pragma unroll
    for (int sft = 1; sft < 64; sft <<= 1) {
        s0 += __shfl_xor(s0, sft);
        s1 += __shfl_xor(s1, sft);
    }
    float rs0 = __builtin_amdgcn_rcpf(s0), rs1 = __builtin_amdgcn_rcpf(s1);
    s_prob0[(2 * lane) * H + w]     = e00 * rs0;
    s_prob0[(2 * lane + 1) * H + w] = e01 * rs0;
    s_prob1[(2 * lane) * H + w]     = e10 * rs1;
    s_prob1[(2 * lane + 1) * H + w] = e11 * rs1;
    __syncthreads();

    // heads: wave w covers m in [32w,32w+32), all 4 heads, both o's, lane = e
    float h00 = 0.f, h01 = 0.f, h02 = 0.f, h03 = 0.f;
    float h10 = 0.f, h11 = 0.f, h12 = 0.f, h13 = 0.f;
    {
        union { uint4 u4[4]; __half2 h2[16]; } mu;
        mu.u4[0] = mr[0]; mu.u4[1] = mr[1]; mu.u4[2] = mr[2]; mu.u4[3] = mr[3];
        const int mbase = 32 * w;
        #pragma unroll 8
        for (int j = 0; j < 16; ++j) {
            float2 mv = __half22float2(mu.h2[j]);
            int m = mbase + 2 * j;
            float4 pa = *(const float4*)(&s_prob0[m * 4]);
            float4 pb = *(const float4*)(&s_prob0[(m + 1) * 4]);
            h00 = fmaf(pa.x, mv.x, h00); h01 = fmaf(pa.y, mv.x, h01);
            h02 = fmaf(pa.z, mv.x, h02); h03 = fmaf(pa.w, mv.x, h03);
            h00 = fmaf(pb.x, mv.y, h00); h01 = fmaf(pb.y, mv.y, h01);
            h02 = fmaf(pb.z, mv.y, h02); h03 = fmaf(pb.w, mv.y, h03);
            float4 pc = *(const float4*)(&s_prob1[m * 4]);
            float4 pd = *(const float4*)(&s_prob1[(m + 1) * 4]);
            h10 = fmaf(pc.x, mv.x, h10); h11 = fmaf(pc.y, mv.x, h11);
            h12 = fmaf(pc.z, mv.x, h12); h13 = fmaf(pc.w, mv.x, h13);
            h10 = fmaf(pd.x, mv.y, h10); h11 = fmaf(pd.y, mv.y, h11);
            h12 = fmaf(pd.z, mv.y, h12); h13 = fmaf(pd.w, mv.y, h13);
        }
    }
    s_part0[0 * 256 + w * 64 + lane] = h00;
    s_part0[1 * 256 + w * 64 + lane] = h01;
    s_part0[2 * 256 + w * 64 + lane] = h02;
    s_part0[3 * 256 + w * 64 + lane] = h03;
    s_part1[0 * 256 + w * 64 + lane] = h10;
    s_part1[1 * 256 + w * 64 + lane] = h11;
    s_part1[2 * 256 + w * 64 + lane] = h12;
    s_part1[3 * 256 + w * 64 + lane] = h13;
    __syncthreads();
    // heads value: thread t -> (h = w, e = lane), f32 (no fp16 round-trip)
    float hv0 = s_part0[w * 256 + lane] + s_part0[w * 256 + 64 + lane]
              + s_part0[w * 256 + 128 + lane] + s_part0[w * 256 + 192 + lane];
    float hv1 = s_part1[w * 256 + lane] + s_part1[w * 256 + 64 + lane]
              + s_part1[w * 256 + 128 + lane] + s_part1[w * 256 + 192 + lane];
    hv0 = (hv0 > 0.f) ? hv0 : 0.01f * hv0;
    hv1 = (hv1 > 0.f) ? hv1 : 0.01f * hv1;

    // fused output projection: wave w owns rows j = w*64..w*64+63 of W_rh;
    // heads[j] = lane (j&63)'s hv via readlane; lane = e' (coalesced W_rh dword)
    {
        float acc0 = 0.f, acc1 = 0.f;
        const float* Wp = W_rh + (w * 64) * 64 + lane;
        #pragma unroll 8
        for (int jj = 0; jj < 64; ++jj) {
            float wv = Wp[jj * 64];
            float hj0 = rl(hv0, jj);
            float hj1 = rl(hv1, jj);
            acc0 = fmaf(hj0, wv, acc0);
            acc1 = fmaf(hj1, wv, acc1);
        }
        s_po0[w * 64 + lane] = acc0;
        s_po1[w * 64 + lane] = acc1;
    }
    __syncthreads();
    if (t < 64) {
        float o = s_po0[t] + s_po0[64 + t] + s_po0[128 + t] + s_po0[192 + t] + b_rh[t];
        out[(size_t)bo0 * 64 + t] = o;
    } else if (t < 128) {
        int e2 = t - 64;
        float o = s_po1[e2] + s_po1[64 + e2] + s_po1[128 + e2] + s_po1[192 + e2] + b_rh[e2];
        out[(size_t)bo1 * 64 + e2] = o;
    }
}

extern "C" void kernel_launch(void* const* d_in, const int* in_sizes, int n_in,
                              void* d_out, int out_size, void* d_ws, size_t ws_size,
                              hipStream_t stream) {
    const float* query   = (const float*)d_in[0];
    const float* context = (const float*)d_in[1];
    const float* memory  = (const float*)d_in[2];
    const float* W_ch    = (const float*)d_in[3];
    const float* b_ch    = (const float*)d_in[4];
    const float* w_logit = (const float*)d_in[5];
    const float* b_logit = (const float*)d_in[6];
    const float* W_rh    = (const float*)d_in[7];
    const float* b_rh    = (const float*)d_in[8];
    const float* temp    = (const float*)d_in[9];
    float* out = (float*)d_out;

    // workspace carve: ctx_Eh 512K | mem_T 512K | q_E 2M
    __half* ctx_Eh  = (__half*)d_ws;
    __half* mem_T   = ctx_Eh + (size_t)B * E * M;
    float*  q_E     = (float*)(mem_T + (size_t)B * E * M);

    prep_kernel<<<576, 256, 0, stream>>>(query, context, memory, W_ch, b_ch,
                                         ctx_Eh, mem_T, q_E);
    attn_main<<<B * O / 2, 256, 0, stream>>>(ctx_Eh, mem_T, q_E, w_logit,
                                             b_logit, temp, W_rh, b_rh, out);
}